// Round 3
// baseline (318.371 us; speedup 1.0000x reference)
//
#include <hip/hip_runtime.h>

// Problem constants (fixed by setup_inputs): N=1, P=3, C=32, H=W=256.
#define PP 3
#define CC 32
#define HH 256
#define WW 256
#define HWP (HH * WW)   // 65536 pixels per plane

typedef float vfloat4 __attribute__((ext_vector_type(4)));  // clang-native, OK for nontemporal builtins

// ws layout (floats): [0, PP*HWP*CC) : transposed features [p][pix][c]

// ---------------------------------------------------------------------------
// Transpose [P][C][H*W] -> [P][H*W][C] so that all 32 channels of one texel
// are one contiguous 128B-aligned chunk (gather becomes 8-lane float4 loads).
// ---------------------------------------------------------------------------
__global__ void tp_transpose(const float* __restrict__ in,
                             float* __restrict__ out) {
    __shared__ float tile[CC][33];   // +1 pad: store-phase reads stay ~2-way
    const int p   = blockIdx.y;
    const int pb  = blockIdx.x * 32;     // pixel base of this tile
    const int tid = threadIdx.x;

    // Load: 32 consecutive pixels per channel row (coalesced).
    const int j     = tid & 31;
    const int cbase = tid >> 5;          // 0..7
    const float* ip = in + (size_t)p * CC * HWP + pb + j;
#pragma unroll
    for (int it = 0; it < 4; ++it) {
        int c = cbase + it * 8;
        tile[c][j] = ip[(size_t)c * HWP];
    }
    __syncthreads();

    // Store: per pixel, 8 lanes write float4 over channels (coalesced).
    const int c4 = tid & 7;
    const int jj = tid >> 3;             // 0..31
    vfloat4 v;
    v.x = tile[c4 * 4 + 0][jj];
    v.y = tile[c4 * 4 + 1][jj];
    v.z = tile[c4 * 4 + 2][jj];
    v.w = tile[c4 * 4 + 3][jj];
    vfloat4* op = (vfloat4*)out + ((size_t)p * HWP + pb + jj) * 8 + c4;
    *op = v;
}

// ---------------------------------------------------------------------------
// Fused sampler: one thread = one (sample, channel-quad) for ALL 3 planes.
//  - coords staged once per block via coalesced LDS load (was 24x redundant)
//  - plane inverses computed per-block in LDS (drops the init kernel)
//  - 12 independent float4 gathers in flight per thread (MLP 12)
//  - non-temporal stores keep the 201 MB out-stream from thrashing L2
// ---------------------------------------------------------------------------
__global__ __launch_bounds__(256) void tp_sample_fused(
        const float* __restrict__ coords,
        const vfloat4* __restrict__ feat_t,  // [p][pix][c] as float4 chunks
        const float* __restrict__ axes,      // [3,3,3]
        const int* __restrict__ box_warp_bits,
        vfloat4* __restrict__ out,
        int M) {
    __shared__ float sc[96];     // 32 samples x 3 coords
    __shared__ float siv[27];    // scaled inverse plane matrices
    const int tid = threadIdx.x;
    const int mb  = blockIdx.x * 32;

    if (tid < 96 && mb * 3 + tid < M * 3) sc[tid] = coords[(size_t)mb * 3 + tid];
    if (tid < PP) {
        int bits = *box_warp_bits;
        float bw = (bits >= 1 && bits <= 100000) ? (float)bits
                                                 : __int_as_float(bits);
        const float* a = axes + tid * 9;
        float a00 = a[0], a01 = a[1], a02 = a[2];
        float a10 = a[3], a11 = a[4], a12 = a[5];
        float a20 = a[6], a21 = a[7], a22 = a[8];
        float det = a00 * (a11 * a22 - a12 * a21)
                  - a01 * (a10 * a22 - a12 * a20)
                  + a02 * (a10 * a21 - a11 * a20);
        float s = (2.0f / bw) / det;
        float* o = siv + tid * 9;
        o[0] = (a11 * a22 - a12 * a21) * s;
        o[1] = (a02 * a21 - a01 * a22) * s;
        o[2] = (a01 * a12 - a02 * a11) * s;
        o[3] = (a12 * a20 - a10 * a22) * s;
        o[4] = (a00 * a22 - a02 * a20) * s;
        o[5] = (a02 * a10 - a00 * a12) * s;
        o[6] = (a10 * a21 - a11 * a20) * s;
        o[7] = (a01 * a20 - a00 * a21) * s;
        o[8] = (a00 * a11 - a01 * a10) * s;
    }
    __syncthreads();

    const int c4 = tid & 7;
    const int ml = tid >> 3;             // 0..31
    const int m  = mb + ml;
    if (m >= M) return;

    const float cx = sc[ml * 3 + 0];
    const float cy = sc[ml * 3 + 1];
    const float cz = sc[ml * 3 + 2];

    int   off[PP][4];
    float wt[PP][4];
#pragma unroll
    for (int p = 0; p < PP; ++p) {
        const float* iv = siv + p * 9;
        const float px = cx * iv[0] + cy * iv[3] + cz * iv[6];
        const float py = cx * iv[1] + cy * iv[4] + cz * iv[7];
        const float ix = (px + 1.0f) * 0.5f * (float)(WW - 1);
        const float iy = (py + 1.0f) * 0.5f * (float)(HH - 1);
        const float fx0 = floorf(ix), fy0 = floorf(iy);
        const float fx = ix - fx0, fy = iy - fy0;
        int x0 = (int)fx0, y0 = (int)fy0;
        int x1 = x0 + 1,   y1 = y0 + 1;
        x0 = min(max(x0, 0), WW - 1); x1 = min(max(x1, 0), WW - 1);
        y0 = min(max(y0, 0), HH - 1); y1 = min(max(y1, 0), HH - 1);
        wt[p][0] = (1.0f - fx) * (1.0f - fy);
        wt[p][1] = fx * (1.0f - fy);
        wt[p][2] = (1.0f - fx) * fy;
        wt[p][3] = fx * fy;
        const int pbase = p * (HWP * 8) + c4;
        off[p][0] = pbase + (y0 * WW + x0) * 8;
        off[p][1] = pbase + (y0 * WW + x1) * 8;
        off[p][2] = pbase + (y1 * WW + x0) * 8;
        off[p][3] = pbase + (y1 * WW + x1) * 8;
    }

    // Issue all 12 gathers back-to-back (independent -> deep vmcnt pipeline).
    vfloat4 v[PP][4];
#pragma unroll
    for (int p = 0; p < PP; ++p)
#pragma unroll
        for (int k = 0; k < 4; ++k)
            v[p][k] = feat_t[off[p][k]];

#pragma unroll
    for (int p = 0; p < PP; ++p) {
        vfloat4 r;
        r.x = v[p][0].x * wt[p][0] + v[p][1].x * wt[p][1]
            + v[p][2].x * wt[p][2] + v[p][3].x * wt[p][3];
        r.y = v[p][0].y * wt[p][0] + v[p][1].y * wt[p][1]
            + v[p][2].y * wt[p][2] + v[p][3].y * wt[p][3];
        r.z = v[p][0].z * wt[p][0] + v[p][1].z * wt[p][1]
            + v[p][2].z * wt[p][2] + v[p][3].z * wt[p][3];
        r.w = v[p][0].w * wt[p][0] + v[p][1].w * wt[p][1]
            + v[p][2].w * wt[p][2] + v[p][3].w * wt[p][3];
        __builtin_nontemporal_store(r, &out[((size_t)p * M + m) * 8 + c4]);
    }
}

extern "C" void kernel_launch(void* const* d_in, const int* in_sizes, int n_in,
                              void* d_out, int out_size, void* d_ws, size_t ws_size,
                              hipStream_t stream) {
    const float* feats  = (const float*)d_in[0];   // [1,3,32,256,256] f32
    const float* coords = (const float*)d_in[1];   // [1,M,3] f32
    const float* axes   = (const float*)d_in[2];   // [3,3,3] f32
    const int*   bw     = (const int*)d_in[3];     // scalar
    const int M = in_sizes[1] / 3;

    float* trans = (float*)d_ws;                   // P*HWP*CC floats

    tp_transpose<<<dim3(HWP / 32, PP), 256, 0, stream>>>(feats, trans);
    tp_sample_fused<<<dim3((M + 31) / 32), 256, 0, stream>>>(
        coords, (const vfloat4*)trans, axes, bw, (vfloat4*)d_out, M);
}

// Round 4
// 297.989 us; speedup vs baseline: 1.0684x; 1.0684x over previous
//
#include <hip/hip_runtime.h>

// Problem constants (fixed by setup_inputs): N=1, P=3, C=32, H=W=256.
#define PP 3
#define CC 32
#define HH 256
#define WW 256
#define HWP (HH * WW)     // 65536 texels per plane
#define TS 16             // bin tile size (texels)
#define TPW 17            // staged tile width (TS+1 for bilinear border)
#define NTILE 256         // (256/TS)^2 tiles per plane
#define NBINS (PP * NTILE)  // 768

typedef float vfloat4 __attribute__((ext_vector_type(4)));

// ---------------------------------------------------------------------------
// Shared helper: scaled inverse plane matrices into LDS (27 floats).
// ---------------------------------------------------------------------------
__device__ inline void init_siv(float* siv, const float* axes, const int* bwbits,
                                int tid) {
    if (tid < PP) {
        int bits = *bwbits;
        float bw = (bits >= 1 && bits <= 100000) ? (float)bits
                                                 : __int_as_float(bits);
        const float* a = axes + tid * 9;
        float a00 = a[0], a01 = a[1], a02 = a[2];
        float a10 = a[3], a11 = a[4], a12 = a[5];
        float a20 = a[6], a21 = a[7], a22 = a[8];
        float det = a00 * (a11 * a22 - a12 * a21)
                  - a01 * (a10 * a22 - a12 * a20)
                  + a02 * (a10 * a21 - a11 * a20);
        float s = (2.0f / bw) / det;
        float* o = siv + tid * 9;
        o[0] = (a11 * a22 - a12 * a21) * s;
        o[1] = (a02 * a21 - a01 * a22) * s;
        o[2] = (a01 * a12 - a02 * a11) * s;
        o[3] = (a12 * a20 - a10 * a22) * s;
        o[4] = (a00 * a22 - a02 * a20) * s;
        o[5] = (a02 * a10 - a00 * a12) * s;
        o[6] = (a10 * a21 - a11 * a20) * s;
        o[7] = (a01 * a20 - a00 * a21) * s;
        o[8] = (a00 * a11 - a01 * a10) * s;
    }
}

// Project sample -> (ix, iy, bin) for plane p.
__device__ inline void project_bin(const float* siv, int p,
                                   float cx, float cy, float cz,
                                   float& ix, float& iy, int& bin) {
    const float* iv = siv + p * 9;
    float px = cx * iv[0] + cy * iv[3] + cz * iv[6];
    float py = cx * iv[1] + cy * iv[4] + cz * iv[7];
    ix = (px + 1.0f) * 0.5f * (float)(WW - 1);
    iy = (py + 1.0f) * 0.5f * (float)(HH - 1);
    int x0 = min(max((int)floorf(ix), 0), WW - 1);
    int y0 = min(max((int)floorf(iy), 0), HH - 1);
    bin = p * NTILE + (y0 >> 4) * (WW / TS) + (x0 >> 4);
}

// ---------------------------------------------------------------------------
// Zero the 768 histogram counters (ws is poisoned each launch).
// ---------------------------------------------------------------------------
__global__ void tp_zero(int* __restrict__ hist) {
    int t = blockIdx.x * blockDim.x + threadIdx.x;
    if (t < NBINS) hist[t] = 0;
}

// ---------------------------------------------------------------------------
// Transpose [P][C][H*W] -> [P][H*W][C] (texel-major, channels contiguous).
// ---------------------------------------------------------------------------
__global__ void tp_transpose(const float* __restrict__ in,
                             float* __restrict__ out) {
    __shared__ float tile[CC][33];
    const int p   = blockIdx.y;
    const int pb  = blockIdx.x * 32;
    const int tid = threadIdx.x;

    const int j     = tid & 31;
    const int cbase = tid >> 5;
    const float* ip = in + (size_t)p * CC * HWP + pb + j;
#pragma unroll
    for (int it = 0; it < 4; ++it) {
        int c = cbase + it * 8;
        tile[c][j] = ip[(size_t)c * HWP];
    }
    __syncthreads();

    const int c4 = tid & 7;
    const int jj = tid >> 3;
    vfloat4 v;
    v.x = tile[c4 * 4 + 0][jj];
    v.y = tile[c4 * 4 + 1][jj];
    v.z = tile[c4 * 4 + 2][jj];
    v.w = tile[c4 * 4 + 3][jj];
    vfloat4* op = (vfloat4*)out + ((size_t)p * HWP + pb + jj) * 8 + c4;
    *op = v;
}

// ---------------------------------------------------------------------------
// Histogram: count samples per (plane, 16x16 tile) bin. Each block handles
// 2048 samples in 8 chunks of 256; LDS-aggregated, 768 global atomics/block.
// ---------------------------------------------------------------------------
__global__ __launch_bounds__(256) void tp_hist(
        const float* __restrict__ coords, const float* __restrict__ axes,
        const int* __restrict__ bwbits, int* __restrict__ hist, int M) {
    __shared__ float sc[768];
    __shared__ float siv[27];
    __shared__ int   lh[NBINS];
    const int tid = threadIdx.x;
    init_siv(siv, axes, bwbits, tid);
    for (int i = tid; i < NBINS; i += 256) lh[i] = 0;
    __syncthreads();

    const int base = blockIdx.x * 2048;
    for (int it = 0; it < 8; ++it) {
        int mb = base + it * 256;
        __syncthreads();
        for (int i = tid; i < 768; i += 256) {
            int gi = mb * 3 + i;
            sc[i] = (gi < M * 3) ? coords[gi] : 0.0f;
        }
        __syncthreads();
        int m = mb + tid;
        if (m < M) {
            float cx = sc[tid * 3], cy = sc[tid * 3 + 1], cz = sc[tid * 3 + 2];
#pragma unroll
            for (int p = 0; p < PP; ++p) {
                float ix, iy; int bin;
                project_bin(siv, p, cx, cy, cz, ix, iy, bin);
                atomicAdd(&lh[bin], 1);
            }
        }
    }
    __syncthreads();
    for (int i = tid; i < NBINS; i += 256)
        if (lh[i]) atomicAdd(&hist[i], lh[i]);
}

// ---------------------------------------------------------------------------
// Exclusive scan of 768 bins (one block); writes bin_start and cursor copy.
// ---------------------------------------------------------------------------
__global__ __launch_bounds__(256) void tp_scan(const int* __restrict__ hist,
                                               int* __restrict__ bin_start,
                                               int* __restrict__ cursor) {
    __shared__ int ps[256];
    const int t = threadIdx.x;
    int a = hist[t * 3], b = hist[t * 3 + 1], c = hist[t * 3 + 2];
    ps[t] = a + b + c;
    __syncthreads();
    for (int off = 1; off < 256; off <<= 1) {
        int v = ps[t];
        int u = (t >= off) ? ps[t - off] : 0;
        __syncthreads();
        ps[t] = v + u;
        __syncthreads();
    }
    int excl = (t == 0) ? 0 : ps[t - 1];
    bin_start[t * 3]     = excl;
    bin_start[t * 3 + 1] = excl + a;
    bin_start[t * 3 + 2] = excl + a + b;
    cursor[t * 3]     = excl;
    cursor[t * 3 + 1] = excl + a;
    cursor[t * 3 + 2] = excl + a + b;
}

// ---------------------------------------------------------------------------
// Scatter records {m, ix, iy} grouped by bin. Count locally (phase 1),
// reserve global ranges (phase 2), recompute+write (phase 3).
// ---------------------------------------------------------------------------
__global__ __launch_bounds__(256) void tp_scatter(
        const float* __restrict__ coords, const float* __restrict__ axes,
        const int* __restrict__ bwbits, int* __restrict__ cursor,
        float* __restrict__ rec, int M) {
    __shared__ float sc[768];
    __shared__ float siv[27];
    __shared__ int   lcnt[NBINS];
    __shared__ int   lbase[NBINS];
    const int tid = threadIdx.x;
    init_siv(siv, axes, bwbits, tid);
    for (int i = tid; i < NBINS; i += 256) lcnt[i] = 0;
    __syncthreads();

    const int base = blockIdx.x * 2048;
    // phase 1: local counts
    for (int it = 0; it < 8; ++it) {
        int mb = base + it * 256;
        __syncthreads();
        for (int i = tid; i < 768; i += 256) {
            int gi = mb * 3 + i;
            sc[i] = (gi < M * 3) ? coords[gi] : 0.0f;
        }
        __syncthreads();
        int m = mb + tid;
        if (m < M) {
            float cx = sc[tid * 3], cy = sc[tid * 3 + 1], cz = sc[tid * 3 + 2];
#pragma unroll
            for (int p = 0; p < PP; ++p) {
                float ix, iy; int bin;
                project_bin(siv, p, cx, cy, cz, ix, iy, bin);
                atomicAdd(&lcnt[bin], 1);
            }
        }
    }
    __syncthreads();
    // phase 2: reserve global ranges, reset local counters
    for (int i = tid; i < NBINS; i += 256) {
        int c = lcnt[i];
        lbase[i] = (c > 0) ? atomicAdd(&cursor[i], c) : 0;
        lcnt[i] = 0;
    }
    __syncthreads();
    // phase 3: recompute + write records
    for (int it = 0; it < 8; ++it) {
        int mb = base + it * 256;
        __syncthreads();
        for (int i = tid; i < 768; i += 256) {
            int gi = mb * 3 + i;
            sc[i] = (gi < M * 3) ? coords[gi] : 0.0f;
        }
        __syncthreads();
        int m = mb + tid;
        if (m < M) {
            float cx = sc[tid * 3], cy = sc[tid * 3 + 1], cz = sc[tid * 3 + 2];
#pragma unroll
            for (int p = 0; p < PP; ++p) {
                float ix, iy; int bin;
                project_bin(siv, p, cx, cy, cz, ix, iy, bin);
                int slot = lbase[bin] + atomicAdd(&lcnt[bin], 1);
                rec[(size_t)slot * 3]     = __int_as_float(m);
                rec[(size_t)slot * 3 + 1] = ix;
                rec[(size_t)slot * 3 + 2] = iy;
            }
        }
    }
}

// ---------------------------------------------------------------------------
// Gather: one block per bin. Stage the 17x17x32ch tile in LDS (37 KB, 4
// blocks/CU), then serve all the bin's samples from LDS. 8 lanes/sample
// (c4 quads); NT 128 B/sample output stores.
// ---------------------------------------------------------------------------
__global__ __launch_bounds__(256) void tp_gather(
        const float* __restrict__ rec, const vfloat4* __restrict__ feat_t,
        const int* __restrict__ hist, const int* __restrict__ bin_start,
        vfloat4* __restrict__ out, int M) {
    __shared__ vfloat4 tile[TPW * TPW * 8];   // 36,992 B, swizzled
    __shared__ float   sr[96];                // 32 staged records
    const int bin = blockIdx.x;
    const int p  = bin >> 8;
    const int rr = bin & 255;
    const int ty = rr >> 4, tx = rr & 15;
    const int cnt   = hist[bin];
    const int start = bin_start[bin];
    const int tid = threadIdx.x;

    for (int i = tid; i < TPW * TPW * 8; i += 256) {
        int texel = i >> 3, c4 = i & 7;
        int yy = texel / TPW, xx = texel - yy * TPW;
        int gy = min(ty * TS + yy, HH - 1);
        int gx = min(tx * TS + xx, WW - 1);
        tile[texel * 8 + ((c4 + texel) & 7)] =
            feat_t[((size_t)p * HWP + gy * WW + gx) * 8 + c4];
    }

    const int c4 = tid & 7;
    const int ml = tid >> 3;
    for (int b = 0; b < cnt; b += 32) {
        int nb = min(32, cnt - b);
        __syncthreads();
        if (tid < nb * 3) sr[tid] = rec[(size_t)(start + b) * 3 + tid];
        __syncthreads();
        if (ml < nb) {
            int   m  = __float_as_int(sr[ml * 3]);
            float ix = sr[ml * 3 + 1], iy = sr[ml * 3 + 2];
            float fx0 = floorf(ix), fy0 = floorf(iy);
            float fx = ix - fx0, fy = iy - fy0;
            int x0 = (int)fx0, y0 = (int)fy0;
            int cx0 = min(max(x0, 0), WW - 1), cx1 = min(max(x0 + 1, 0), WW - 1);
            int cy0 = min(max(y0, 0), HH - 1), cy1 = min(max(y0 + 1, 0), HH - 1);
            int lx0 = cx0 - tx * TS, lx1 = cx1 - tx * TS;
            int ly0 = cy0 - ty * TS, ly1 = cy1 - ty * TS;
            int t00 = ly0 * TPW + lx0, t01 = ly0 * TPW + lx1;
            int t10 = ly1 * TPW + lx0, t11 = ly1 * TPW + lx1;
            vfloat4 v00 = tile[t00 * 8 + ((c4 + t00) & 7)];
            vfloat4 v01 = tile[t01 * 8 + ((c4 + t01) & 7)];
            vfloat4 v10 = tile[t10 * 8 + ((c4 + t10) & 7)];
            vfloat4 v11 = tile[t11 * 8 + ((c4 + t11) & 7)];
            float w00 = (1.0f - fx) * (1.0f - fy);
            float w01 = fx * (1.0f - fy);
            float w10 = (1.0f - fx) * fy;
            float w11 = fx * fy;
            vfloat4 res = v00 * w00 + v01 * w01 + v10 * w10 + v11 * w11;
            __builtin_nontemporal_store(res, &out[((size_t)p * M + m) * 8 + c4]);
        }
    }
}

extern "C" void kernel_launch(void* const* d_in, const int* in_sizes, int n_in,
                              void* d_out, int out_size, void* d_ws, size_t ws_size,
                              hipStream_t stream) {
    const float* feats  = (const float*)d_in[0];   // [1,3,32,256,256] f32
    const float* coords = (const float*)d_in[1];   // [1,M,3] f32
    const float* axes   = (const float*)d_in[2];   // [3,3,3] f32
    const int*   bw     = (const int*)d_in[3];     // scalar
    const int M = in_sizes[1] / 3;

    // ws layout
    char* wsp = (char*)d_ws;
    float* trans     = (float*)wsp;                              // 25,165,824 B
    int*   hist      = (int*)(wsp + (size_t)25165824);           // 3072 B
    int*   bin_start = (int*)(wsp + (size_t)25165824 + 3072);    // 3072 B
    int*   cursor    = (int*)(wsp + (size_t)25165824 + 6144);    // 3072 B
    float* rec       = (float*)(wsp + (size_t)25165824 + 9216);  // 3*M*12 B

    const int nblk = (M + 2047) / 2048;

    tp_zero<<<(NBINS + 255) / 256, 256, 0, stream>>>(hist);
    tp_transpose<<<dim3(HWP / 32, PP), 256, 0, stream>>>(feats, trans);
    tp_hist<<<nblk, 256, 0, stream>>>(coords, axes, bw, hist, M);
    tp_scan<<<1, 256, 0, stream>>>(hist, bin_start, cursor);
    tp_scatter<<<nblk, 256, 0, stream>>>(coords, axes, bw, cursor, rec, M);
    tp_gather<<<NBINS, 256, 0, stream>>>(rec, (const vfloat4*)trans, hist,
                                         bin_start, (vfloat4*)d_out, M);
}